// Round 10
// baseline (318.188 us; speedup 1.0000x reference)
//
#include <hip/hip_runtime.h>
#include <hip/hip_bf16.h>

#define H 2048
#define K 1024
#define R 3
#define BB 8
#define S 2048

typedef __bf16 bf16x8 __attribute__((ext_vector_type(8)));
typedef float f32x4 __attribute__((ext_vector_type(4)));
typedef unsigned short ushort8 __attribute__((ext_vector_type(8)));

static __device__ __forceinline__ unsigned short f2bf(float f) {
    unsigned int u = __float_as_uint(f);
    u += 0x7FFFu + ((u >> 16) & 1u);   // round-to-nearest-even
    return (unsigned short)(u >> 16);
}

#define GLOAD_LDS16(g, l)                                                      \
    __builtin_amdgcn_global_load_lds(                                          \
        (const __attribute__((address_space(1))) void*)(g),                    \
        (__attribute__((address_space(3))) void*)(l), 16, 0, 0)

// ---------------- convert hidden f32 -> bf16 ----------------
__global__ __launch_bounds__(256) void cvt_hs(const float* __restrict__ in,
                                              unsigned short* __restrict__ out,
                                              int n8) {
    int stride = gridDim.x * blockDim.x;
    for (int i = blockIdx.x * blockDim.x + threadIdx.x; i < n8; i += stride) {
        const float4* p = (const float4*)(in + (size_t)i * 8);
        float4 a = p[0], b = p[1];
        union { unsigned short us[8]; ushort8 v; } o;
        o.us[0] = f2bf(a.x); o.us[1] = f2bf(a.y);
        o.us[2] = f2bf(a.z); o.us[3] = f2bf(a.w);
        o.us[4] = f2bf(b.x); o.us[5] = f2bf(b.y);
        o.us[6] = f2bf(b.z); o.us[7] = f2bf(b.w);
        *(ushort8*)(out + (size_t)i * 8) = o.v;
    }
}

// -------- transpose+convert: in f32 [rows][cols] -> out bf16 [cols][rows] ----
__global__ __launch_bounds__(256) void tpose(const float* __restrict__ in,
                                             unsigned short* __restrict__ out,
                                             int rows, int cols) {
    __shared__ float tile[32][33];
    int rr = blockIdx.z;
    const float* ip = in + (size_t)rr * rows * cols;
    unsigned short* op = out + (size_t)rr * rows * cols;
    int x = blockIdx.x * 32 + threadIdx.x;
    int y0 = blockIdx.y * 32 + threadIdx.y;
#pragma unroll
    for (int j = 0; j < 32; j += 8)
        tile[threadIdx.y + j][threadIdx.x] = ip[(size_t)(y0 + j) * cols + x];
    __syncthreads();
    int ox = blockIdx.y * 32 + threadIdx.x;
    int oy0 = blockIdx.x * 32 + threadIdx.y;
#pragma unroll
    for (int j = 0; j < 32; j += 8)
        op[(size_t)(oy0 + j) * rows + ox] = f2bf(tile[threadIdx.x][threadIdx.y + j]);
}

// ==== 256x128 4-phase/pair NT GEMM, BK=64, ring-3 LDS, 1-phase READ-AHEAD ====
// 8 waves 2Mx4N; per-wave C = 128x32 -> acc[8][2] = 64 VGPR. Fragment sets
// A0/A1 (32 each), B0/B1 (16 each): every phase's MFMA consumes fragments
// read in the PREVIOUS phase, so the backend's counted lgkmcnt lets the
// current phase's ds_reads drain UNDER the MFMA burst (regs ~180, no spill).
// LDS: 3 slots x 48KB (A 32KB + B 16KB), slot(tile) = tile%3.
// Pair (t,t+1), phases (16 MFMA each):
//  P1: rd A-hi(t)->A1       | stage t+2: A c0,c1          | MFMA A0xB0 (Qlo t)
//      gate vmcnt(2) [forces t+1] barrier
//  P2: rd B(t+1)->B1, A-lo(t+1)->A0 | stage t+2: A c2,c3, B c0,c1 | MFMA A1xB0
//      barrier
//  P3: rd A-hi(t+1)->A1     | stage t+3: A c0,c1          | MFMA A0xB1
//      gate vmcnt(2) [forces t+2] barrier
//  P4: rd B(t+2)->B0, A-lo(t+2)->A0 | stage t+3: A c2,c3, B c0,c1 | MFMA A1xB1
//      barrier
// Gate arithmetic: end-P1 outstanding = t+1(6, prev P3/P4) + P1(2) -> vmcnt(2)
// forces t+1 (needed P2). end-P3 outstanding = t+2(6, P1/P2) + P3(2) ->
// vmcnt(2) forces t+2 (needed P4). Flight >= 2-3 phases. WAR: each staged
// slot's last ds_read completed before the preceding MFMA's lgkm wait (DS
// in-order), >=1 barrier before the stage issues.
// EPI 0: out = bf16 gelu(acc+bias) -> h
// EPI 1: out = bf16 (acc+bias+resid_bf16) IN PLACE over resid; row stats->Part
template <int KC, int EPI>
__global__ __launch_bounds__(512, 2) void gemm_ra(
    const unsigned short* __restrict__ A, const unsigned short* __restrict__ Bt,
    const int* __restrict__ role, const float* __restrict__ bias,
    const unsigned short* __restrict__ resid, void* __restrict__ Out,
    float2* __restrict__ Part, int N) {
    constexpr int NT = KC / 64;          // even, >= 16
    __shared__ char smem[147456];        // 3 x 49152
    const int tid = threadIdx.x;
    const int wid = tid >> 6, lane = tid & 63;
    const int wm = wid >> 2, wn = wid & 3;
    const int lr = lane & 15, lc = lane >> 4;

    const int nx = N >> 7;               // N/128 n-tiles
    const int cpx = gridDim.x >> 3;
    const int orig = (blockIdx.x & 7) * cpx + (blockIdx.x >> 3);
    const int tn = orig % nx;
    const int tmz = orig / nx;
    const int tm = tmz & 7;              // S/256 = 8 m-tiles
    const int z = tmz >> 3;
    const int r = role[z];

    const char* Ab = (const char*)(A + ((size_t)z * S + (size_t)tm * 256) * KC);
    const char* Bb = (const char*)(Bt + ((size_t)r * N + (size_t)tn * 128) * KC);

    const int P16 = tid * 16;

    // A: 256 rows x 128B = 4 calls (c 0-3); B: 128 rows = 2 calls (c 0-1)
#define STGA(sb, kt, c)                                                        \
    do {                                                                       \
        int P_ = (c) * 8192 + P16;                                             \
        int L_ = P_ ^ (((P_ >> 7) & 7) << 4);                                  \
        const char* g_ = Ab + (size_t)(L_ >> 7) * (KC * 2) +                   \
                         (size_t)(kt) * 128 + (L_ & 127);                      \
        GLOAD_LDS16(g_, smem + (sb) + P_);                                     \
    } while (0)
#define STGB(sb, kt, c)                                                        \
    do {                                                                       \
        int P_ = (c) * 8192 + P16;                                             \
        int L_ = P_ ^ (((P_ >> 7) & 7) << 4);                                  \
        const char* g_ = Bb + (size_t)(L_ >> 7) * (KC * 2) +                   \
                         (size_t)(kt) * 128 + (L_ & 127);                      \
        GLOAD_LDS16(g_, smem + (sb) + 32768 + P_);                             \
    } while (0)

    // prologue: stage t0 -> slot0, t1 -> slot1; force t0; pre-read A-lo(0),B(0)
    STGA(0, 0, 0); STGA(0, 0, 1); STGA(0, 0, 2); STGA(0, 0, 3);
    STGB(0, 0, 0); STGB(0, 0, 1);
    STGA(49152, 1, 0); STGA(49152, 1, 1); STGA(49152, 1, 2); STGA(49152, 1, 3);
    STGB(49152, 1, 0); STGB(49152, 1, 1);
    asm volatile("s_waitcnt vmcnt(6)" ::: "memory");
    asm volatile("s_barrier" ::: "memory");

    f32x4 acc[8][2] = {};
    const int swz = (lr & 7) << 4;
    const int ck0 = (lc << 4) ^ swz;
    const int ck1 = ck0 ^ 0x40;
    const char* sm = smem;

    bf16x8 A0[4][2], A1[4][2], B0[2][2], B1[2][2];

#define RDA(dst, ih, SB)                                                       \
    _Pragma("unroll") for (int i_ = 0; i_ < 4; i_++) {                         \
        int rb_ = (wm * 128 + ((ih) + i_) * 16 + lr) << 7;                     \
        dst[i_][0] = *(const bf16x8*)(sm + (SB) + rb_ + ck0);                  \
        dst[i_][1] = *(const bf16x8*)(sm + (SB) + rb_ + ck1); }
#define RDB(dst, SB)                                                           \
    _Pragma("unroll") for (int j_ = 0; j_ < 2; j_++) {                         \
        int rb_ = (wn * 32 + j_ * 16 + lr) << 7;                               \
        dst[j_][0] = *(const bf16x8*)(sm + (SB) + 32768 + rb_ + ck0);          \
        dst[j_][1] = *(const bf16x8*)(sm + (SB) + 32768 + rb_ + ck1); }
#define QMFMA(ar, br, IOFF)                                                    \
    _Pragma("unroll") for (int kk = 0; kk < 2; kk++)                           \
    _Pragma("unroll") for (int i_ = 0; i_ < 4; i_++)                           \
    _Pragma("unroll") for (int j_ = 0; j_ < 2; j_++)                           \
        acc[(IOFF) + i_][j_] = __builtin_amdgcn_mfma_f32_16x16x32_bf16(        \
            ar[i_][kk], br[j_][kk], acc[(IOFF) + i_][j_], 0, 0, 0);
#define BAR() asm volatile("s_barrier" ::: "memory")

    RDA(A0, 0, 0);       // A-lo(0)
    RDB(B0, 0);          // B(0)

    int s0b = 0, s1b = 49152, s2b = 98304;   // slots t%3, (t+1)%3, (t+2)%3
#pragma unroll 1
    for (int t = 0; t < NT; t += 2) {
        const bool pf = (t + 2) < NT;
        // ---- P1 ----
        RDA(A1, 4, s0b);
        if (pf) { STGA(s2b, t + 2, 0); STGA(s2b, t + 2, 1); }
        __builtin_amdgcn_s_setprio(1); QMFMA(A0, B0, 0);
        __builtin_amdgcn_s_setprio(0);
        if (pf) asm volatile("s_waitcnt vmcnt(2)" ::: "memory");
        else    asm volatile("s_waitcnt vmcnt(0)" ::: "memory");
        BAR();
        // ---- P2 ----
        RDB(B1, s1b); RDA(A0, 0, s1b);
        if (pf) { STGA(s2b, t + 2, 2); STGA(s2b, t + 2, 3);
                  STGB(s2b, t + 2, 0); STGB(s2b, t + 2, 1); }
        __builtin_amdgcn_s_setprio(1); QMFMA(A1, B0, 4);
        __builtin_amdgcn_s_setprio(0); BAR();
        // ---- P3 ----
        RDA(A1, 4, s1b);
        if (pf) { STGA(s0b, t + 3, 0); STGA(s0b, t + 3, 1); }
        __builtin_amdgcn_s_setprio(1); QMFMA(A0, B1, 0);
        __builtin_amdgcn_s_setprio(0);
        if (pf) asm volatile("s_waitcnt vmcnt(2)" ::: "memory");
        BAR();
        // ---- P4 ----
        if (pf) { RDB(B0, s2b); RDA(A0, 0, s2b); }
        if (pf) { STGA(s0b, t + 3, 2); STGA(s0b, t + 3, 3);
                  STGB(s0b, t + 3, 0); STGB(s0b, t + 3, 1); }
        __builtin_amdgcn_s_setprio(1); QMFMA(A1, B1, 4);
        __builtin_amdgcn_s_setprio(0); BAR();
        int tmp = s0b; s0b = s2b; s2b = s1b; s1b = tmp;
    }
#undef STGA
#undef STGB
#undef RDA
#undef RDB
#undef QMFMA
#undef BAR

    // ---- epilogue ----
    const int base_m = tm * 256 + wm * 128;
    const int base_n = tn * 128 + wn * 32;
    float bn[2];
    const float* bp = bias + (size_t)r * N + base_n;
#pragma unroll
    for (int j = 0; j < 2; j++) bn[j] = bp[j * 16 + lr];

    if (EPI == 0) {
        unsigned short* o = (unsigned short*)Out;
#pragma unroll
        for (int i = 0; i < 8; i++) {
#pragma unroll
            for (int j = 0; j < 2; j++) {
#pragma unroll
                for (int q = 0; q < 4; q++) {
                    size_t grow = (size_t)z * S + base_m + i * 16 + lc * 4 + q;
                    int col = base_n + j * 16 + lr;
                    float x = acc[i][j][q] + bn[j];
                    float g = 0.5f * x * (1.0f + erff(x * 0.70710678118654752f));
                    o[grow * N + col] = f2bf(g);
                }
            }
        }
    } else {
        unsigned short* o = (unsigned short*)Out;     // y bf16 (in place on resid)
        float* pl = (float*)smem;                     // [8][256] partials
        __syncthreads();
#pragma unroll
        for (int i = 0; i < 8; i++) {
#pragma unroll
            for (int q = 0; q < 4; q++) {
                size_t grow = (size_t)z * S + base_m + i * 16 + lc * 4 + q;
                float s = 0.f, sq = 0.f;
#pragma unroll
                for (int j = 0; j < 2; j++) {
                    int col = base_n + j * 16 + lr;
                    float rv = __uint_as_float(((unsigned)resid[grow * (size_t)N + col]) << 16);
                    float y = acc[i][j][q] + bn[j] + rv;
                    o[grow * (size_t)N + col] = f2bf(y);
                    s += y; sq += y * y;
                }
#pragma unroll
                for (int off = 1; off < 16; off <<= 1) {
                    s  += __shfl_xor(s, off);
                    sq += __shfl_xor(sq, off);
                }
                if (lr == 0) {
                    int rloc = wm * 128 + i * 16 + lc * 4 + q;
                    pl[wn * 256 + rloc] = s;
                    pl[(4 + wn) * 256 + rloc] = sq;
                }
            }
        }
        __syncthreads();
        if (tid < 256) {
            float s  = pl[tid] + pl[256 + tid] + pl[512 + tid] + pl[768 + tid];
            float sq = pl[1024 + tid] + pl[1280 + tid] + pl[1536 + tid] + pl[1792 + tid];
            size_t grow = (size_t)z * S + tm * 256 + tid;
            Part[(size_t)tn * (BB * S) + grow] = make_float2(s, sq);
        }
    }
}

// ------- LayerNorm: partials + y(bf16) -> out(f32), one block per row -------
__global__ __launch_bounds__(256) void ln2(const unsigned short* __restrict__ ybf,
                                           const float2* __restrict__ part,
                                           const int* __restrict__ role,
                                           const float* __restrict__ gamma,
                                           const float* __restrict__ beta,
                                           float* __restrict__ out) {
    int row = blockIdx.x;
    int z = row >> 11;                 // row / S
    int r = role[z];
    float s = 0.f, ss = 0.f;
#pragma unroll
    for (int nb = 0; nb < 16; nb++) {  // H/128 = 16 col-blocks
        float2 p = part[(size_t)nb * (BB * S) + row];
        s += p.x; ss += p.y;
    }
    float mean = s * (1.0f / H);
    float var = ss * (1.0f / H) - mean * mean;
    float rstd = rsqrtf(var + 1e-5f);
    int t = threadIdx.x;
    ushort8 yv = ((const ushort8*)(ybf + (size_t)row * H))[t];
    const float4* gp = (const float4*)(gamma + (size_t)r * H);
    const float4* bp = (const float4*)(beta + (size_t)r * H);
    float4 g0 = gp[2 * t], g1 = gp[2 * t + 1];
    float4 b0 = bp[2 * t], b1 = bp[2 * t + 1];
    float yo[8];
#pragma unroll
    for (int e = 0; e < 8; e++)
        yo[e] = (__uint_as_float(((unsigned)yv[e]) << 16) - mean) * rstd;
    float4 r0, r1;
    r0.x = yo[0] * g0.x + b0.x; r0.y = yo[1] * g0.y + b0.y;
    r0.z = yo[2] * g0.z + b0.z; r0.w = yo[3] * g0.w + b0.w;
    r1.x = yo[4] * g1.x + b1.x; r1.y = yo[5] * g1.y + b1.y;
    r1.z = yo[6] * g1.z + b1.z; r1.w = yo[7] * g1.w + b1.w;
    float4* op = (float4*)(out + (size_t)row * H);
    op[2 * t] = r0;
    op[2 * t + 1] = r1;
}

extern "C" void kernel_launch(void* const* d_in, const int* in_sizes, int n_in,
                              void* d_out, int out_size, void* d_ws, size_t ws_size,
                              hipStream_t stream) {
    const int* role = (const int*)d_in[0];
    const float* hs = (const float*)d_in[1];
    const float* Wd = (const float*)d_in[2];
    const float* bd = (const float*)d_in[3];
    const float* Wu = (const float*)d_in[4];
    const float* bu = (const float*)d_in[5];
    const float* gamma = (const float*)d_in[6];
    const float* beta = (const float*)d_in[7];
    float* out = (float*)d_out;

    char* ws = (char*)d_ws;
    // region A (64 MiB @0): hs_bf (cvt -> G1, resid of G2), then y_bf (G2 -> LN, in place)
    unsigned short* hs_bf = (unsigned short*)ws;
    unsigned short* y_bf = (unsigned short*)ws;
    // region B (12 MiB @64Mi): wd_t (tpose -> G1), then partials (G2 -> LN, 2 MiB)
    unsigned short* wd_t = (unsigned short*)(ws + 67108864);
    float2* part = (float2*)(ws + 67108864);
    // region C (12 MiB @76Mi): wu_t
    unsigned short* wu_t = (unsigned short*)(ws + 67108864 + 12582912);
    // region D (32 MiB @88Mi): h
    unsigned short* h_ws = (unsigned short*)(ws + 67108864 + 2 * 12582912);

    cvt_hs<<<4096, 256, 0, stream>>>(hs, hs_bf, (BB * S * H) / 8);
    dim3 tb(32, 8);
    tpose<<<dim3(K / 32, H / 32, R), tb, 0, stream>>>(Wd, wd_t, H, K);
    tpose<<<dim3(H / 32, K / 32, R), tb, 0, stream>>>(Wu, wu_t, K, H);
    // GEMM1: h = gelu(hs_bf x Wd^T + bd), bf16; (1024/128)*8*8 = 512 blocks
    gemm_ra<H, 0><<<(K / 128) * 8 * BB, 512, 0, stream>>>(hs_bf, wd_t, role, bd,
                                                          nullptr, h_ws, nullptr, K);
    // GEMM2: y = h x Wu^T + bu + hs_bf, bf16 in place + stats; 1024 blocks
    gemm_ra<K, 1><<<(H / 128) * 8 * BB, 512, 0, stream>>>(h_ws, wu_t, role, bu,
                                                          hs_bf, y_bf, part, H);
    ln2<<<BB * S, 256, 0, stream>>>(y_bf, part, role, gamma, beta, out);
}

// Round 11
// 256.537 us; speedup vs baseline: 1.2403x; 1.2403x over previous
//
#include <hip/hip_runtime.h>
#include <hip/hip_bf16.h>

#define H 2048
#define K 1024
#define R 3
#define BB 8
#define S 2048

typedef __bf16 bf16x8 __attribute__((ext_vector_type(8)));
typedef float f32x4 __attribute__((ext_vector_type(4)));
typedef unsigned short ushort8 __attribute__((ext_vector_type(8)));

static __device__ __forceinline__ unsigned short f2bf(float f) {
    unsigned int u = __float_as_uint(f);
    u += 0x7FFFu + ((u >> 16) & 1u);   // round-to-nearest-even
    return (unsigned short)(u >> 16);
}

#define GLOAD_LDS16(g, l)                                                      \
    __builtin_amdgcn_global_load_lds(                                          \
        (const __attribute__((address_space(1))) void*)(g),                    \
        (__attribute__((address_space(3))) void*)(l), 16, 0, 0)

// ---------------- convert hidden f32 -> bf16 ----------------
__global__ __launch_bounds__(256) void cvt_hs(const float* __restrict__ in,
                                              unsigned short* __restrict__ out,
                                              int n8) {
    int stride = gridDim.x * blockDim.x;
    for (int i = blockIdx.x * blockDim.x + threadIdx.x; i < n8; i += stride) {
        const float4* p = (const float4*)(in + (size_t)i * 8);
        float4 a = p[0], b = p[1];
        union { unsigned short us[8]; ushort8 v; } o;
        o.us[0] = f2bf(a.x); o.us[1] = f2bf(a.y);
        o.us[2] = f2bf(a.z); o.us[3] = f2bf(a.w);
        o.us[4] = f2bf(b.x); o.us[5] = f2bf(b.y);
        o.us[6] = f2bf(b.z); o.us[7] = f2bf(b.w);
        *(ushort8*)(out + (size_t)i * 8) = o.v;
    }
}

// -------- transpose+convert: in f32 [rows][cols] -> out bf16 [cols][rows] ----
__global__ __launch_bounds__(256) void tpose(const float* __restrict__ in,
                                             unsigned short* __restrict__ out,
                                             int rows, int cols) {
    __shared__ float tile[32][33];
    int rr = blockIdx.z;
    const float* ip = in + (size_t)rr * rows * cols;
    unsigned short* op = out + (size_t)rr * rows * cols;
    int x = blockIdx.x * 32 + threadIdx.x;
    int y0 = blockIdx.y * 32 + threadIdx.y;
#pragma unroll
    for (int j = 0; j < 32; j += 8)
        tile[threadIdx.y + j][threadIdx.x] = ip[(size_t)(y0 + j) * cols + x];
    __syncthreads();
    int ox = blockIdx.y * 32 + threadIdx.x;
    int oy0 = blockIdx.x * 32 + threadIdx.y;
#pragma unroll
    for (int j = 0; j < 32; j += 8)
        op[(size_t)(oy0 + j) * rows + ox] = f2bf(tile[threadIdx.x][threadIdx.y + j]);
}

// ==== 128x256 NT GEMM, BK=32, ring-3 24KB slots (72KB LDS -> 2 blocks/CU) ====
// TLP design (m97/m114): 2 blocks x 8 waves = 16 waves/CU; one block's
// barrier/vmcnt drain hides under the other block's MFMA waves. Simple
// 1-barrier K-step: {stage t+2 (3 gload_lds); 8 ds_read_b128; 16 MFMA;
// vmcnt(3); barrier}. __launch_bounds__(512,4) caps VGPR at 128 (acc 64 +
// frags 32). Swizzle for 64B rows: 16B-slot = lc ^ ((lr>>1)&3) -- uniform
// 8 lanes per bank-class (minimal, 2-way = free per m136); inverse applied
// on the global staging source (LDS dest linear, rule #21).
// Gates: per iter vmcnt(3) forces tile t+1 (issued last iter), leaves t+2
// flying. WAR: slot (t+2)%3's last readers drained pre-barrier at t-1.
// EPI 0: out = bf16 gelu(acc+bias) -> h
// EPI 1: out = bf16 (acc+bias+resid_bf16) IN PLACE over resid; row stats->Part
template <int KC, int EPI>
__global__ __launch_bounds__(512, 4) void gemm_tlp(
    const unsigned short* __restrict__ A, const unsigned short* __restrict__ Bt,
    const int* __restrict__ role, const float* __restrict__ bias,
    const unsigned short* __restrict__ resid, void* __restrict__ Out,
    float2* __restrict__ Part, int N) {
    constexpr int NT = KC / 32;
    __shared__ char smem[73728];         // 3 x 24576
    const int tid = threadIdx.x;
    const int wid = tid >> 6, lane = tid & 63;
    const int wm = wid >> 2, wn = wid & 3;
    const int lr = lane & 15, lc = lane >> 4;

    const int nx = N >> 8;               // N/256 n-tiles
    const int cpx = gridDim.x >> 3;
    const int orig = (blockIdx.x & 7) * cpx + (blockIdx.x >> 3);
    const int tn = orig % nx;
    const int tmz = orig / nx;
    const int tm = tmz & 15;             // S/128 = 16 m-tiles
    const int z = tmz >> 4;
    const int r = role[z];

    const char* Ab = (const char*)(A + ((size_t)z * S + (size_t)tm * 128) * KC);
    const char* Bb = (const char*)(Bt + ((size_t)r * N + (size_t)tn * 256) * KC);

    const int P16 = tid * 16;            // linear LDS byte offset, one 16B/thr
    // staging source pre-swizzle (loop-invariant parts hoist; only kt varies)
    const int srowA = P16 >> 6;
    const int sslot = ((P16 >> 4) & 3) ^ ((srowA >> 1) & 3);
    const size_t sgA = (size_t)srowA * (KC * 2) + sslot * 16;

#define STGA(sb, kt) GLOAD_LDS16(Ab + sgA + (kt) * 64, smem + (sb) + P16)
#define STGB(sb, kt, c)                                                        \
    GLOAD_LDS16(Bb + (size_t)((c) * 128 + srowA) * (KC * 2) + sslot * 16 +     \
                    (kt) * 64,                                                 \
                smem + (sb) + 8192 + (c) * 8192 + P16)
#define STAGE3(sb, kt) do { STGA(sb, kt); STGB(sb, kt, 0); STGB(sb, kt, 1); } while (0)

    // prologue: stage t0 -> slot0, t1 -> slot1; force t0; leave t1 flying
    STAGE3(0, 0);
    STAGE3(24576, 1);
    asm volatile("s_waitcnt vmcnt(3)" ::: "memory");
    __builtin_amdgcn_s_barrier();

    f32x4 acc[4][4] = {};
    const int ck = (lc ^ ((lr >> 1) & 3)) << 4;   // swizzled 16B-slot
    const char* sm = smem;

    int sA = 0, sB = 24576, sC = 49152;  // slots t%3, (t+1)%3, (t+2)%3
#pragma unroll 1
    for (int t = 0; t < NT; ++t) {
        const bool pf = (t + 2) < NT;
        if (pf) STAGE3(sC, t + 2);
        bf16x8 a[4], b[4];
#pragma unroll
        for (int i = 0; i < 4; i++)
            a[i] = *(const bf16x8*)(sm + sA + ((wm * 64 + i * 16 + lr) << 6) + ck);
#pragma unroll
        for (int j = 0; j < 4; j++)
            b[j] = *(const bf16x8*)(sm + sA + 8192 + ((wn * 64 + j * 16 + lr) << 6) + ck);
        __builtin_amdgcn_s_setprio(1);
#pragma unroll
        for (int i = 0; i < 4; i++)
#pragma unroll
            for (int j = 0; j < 4; j++)
                acc[i][j] = __builtin_amdgcn_mfma_f32_16x16x32_bf16(a[i], b[j], acc[i][j], 0, 0, 0);
        __builtin_amdgcn_s_setprio(0);
        if (t < NT - 1) {
            if (pf) asm volatile("s_waitcnt vmcnt(3)" ::: "memory");
            else    asm volatile("s_waitcnt vmcnt(0)" ::: "memory");
            __builtin_amdgcn_s_barrier();
        }
        int tmp = sA; sA = sB; sB = sC; sC = tmp;
    }
#undef STGA
#undef STGB
#undef STAGE3

    // ---- epilogue ----
    const int base_m = tm * 128 + wm * 64;
    const int base_n = tn * 256 + wn * 64;
    float bn[4];
    const float* bp = bias + (size_t)r * N + base_n;
#pragma unroll
    for (int j = 0; j < 4; j++) bn[j] = bp[j * 16 + lr];

    if (EPI == 0) {
        unsigned short* o = (unsigned short*)Out;
#pragma unroll
        for (int i = 0; i < 4; i++) {
#pragma unroll
            for (int j = 0; j < 4; j++) {
#pragma unroll
                for (int q = 0; q < 4; q++) {
                    size_t grow = (size_t)z * S + base_m + i * 16 + lc * 4 + q;
                    int col = base_n + j * 16 + lr;
                    float x = acc[i][j][q] + bn[j];
                    float g = 0.5f * x * (1.0f + erff(x * 0.70710678118654752f));
                    o[grow * N + col] = f2bf(g);
                }
            }
        }
    } else {
        unsigned short* o = (unsigned short*)Out;     // y bf16 (in place on resid)
        float* pl = (float*)smem;                     // [8][128] partials
        __syncthreads();
#pragma unroll
        for (int i = 0; i < 4; i++) {
#pragma unroll
            for (int q = 0; q < 4; q++) {
                size_t grow = (size_t)z * S + base_m + i * 16 + lc * 4 + q;
                float s = 0.f, sq = 0.f;
#pragma unroll
                for (int j = 0; j < 4; j++) {
                    int col = base_n + j * 16 + lr;
                    float rv = __uint_as_float(((unsigned)resid[grow * (size_t)N + col]) << 16);
                    float y = acc[i][j][q] + bn[j] + rv;
                    o[grow * (size_t)N + col] = f2bf(y);
                    s += y; sq += y * y;
                }
#pragma unroll
                for (int off = 1; off < 16; off <<= 1) {
                    s  += __shfl_xor(s, off);
                    sq += __shfl_xor(sq, off);
                }
                if (lr == 0) {
                    int rloc = wm * 64 + i * 16 + lc * 4 + q;   // 0..127
                    pl[wn * 128 + rloc] = s;
                    pl[512 + wn * 128 + rloc] = sq;
                }
            }
        }
        __syncthreads();
        if (tid < 128) {
            float s  = pl[tid] + pl[128 + tid] + pl[256 + tid] + pl[384 + tid];
            float sq = pl[512 + tid] + pl[640 + tid] + pl[768 + tid] + pl[896 + tid];
            size_t grow = (size_t)z * S + tm * 128 + tid;
            Part[(size_t)tn * (BB * S) + grow] = make_float2(s, sq);
        }
    }
}

// ------- LayerNorm: partials + y(bf16) -> out(f32), one block per row -------
__global__ __launch_bounds__(256) void ln2(const unsigned short* __restrict__ ybf,
                                           const float2* __restrict__ part,
                                           const int* __restrict__ role,
                                           const float* __restrict__ gamma,
                                           const float* __restrict__ beta,
                                           float* __restrict__ out) {
    int row = blockIdx.x;
    int z = row >> 11;                 // row / S
    int r = role[z];
    float s = 0.f, ss = 0.f;
#pragma unroll
    for (int nb = 0; nb < 8; nb++) {   // H/256 = 8 col-blocks
        float2 p = part[(size_t)nb * (BB * S) + row];
        s += p.x; ss += p.y;
    }
    float mean = s * (1.0f / H);
    float var = ss * (1.0f / H) - mean * mean;
    float rstd = rsqrtf(var + 1e-5f);
    int t = threadIdx.x;
    ushort8 yv = ((const ushort8*)(ybf + (size_t)row * H))[t];
    const float4* gp = (const float4*)(gamma + (size_t)r * H);
    const float4* bp = (const float4*)(beta + (size_t)r * H);
    float4 g0 = gp[2 * t], g1 = gp[2 * t + 1];
    float4 b0 = bp[2 * t], b1 = bp[2 * t + 1];
    float yo[8];
#pragma unroll
    for (int e = 0; e < 8; e++)
        yo[e] = (__uint_as_float(((unsigned)yv[e]) << 16) - mean) * rstd;
    float4 r0, r1;
    r0.x = yo[0] * g0.x + b0.x; r0.y = yo[1] * g0.y + b0.y;
    r0.z = yo[2] * g0.z + b0.z; r0.w = yo[3] * g0.w + b0.w;
    r1.x = yo[4] * g1.x + b1.x; r1.y = yo[5] * g1.y + b1.y;
    r1.z = yo[6] * g1.z + b1.z; r1.w = yo[7] * g1.w + b1.w;
    float4* op = (float4*)(out + (size_t)row * H);
    op[2 * t] = r0;
    op[2 * t + 1] = r1;
}

extern "C" void kernel_launch(void* const* d_in, const int* in_sizes, int n_in,
                              void* d_out, int out_size, void* d_ws, size_t ws_size,
                              hipStream_t stream) {
    const int* role = (const int*)d_in[0];
    const float* hs = (const float*)d_in[1];
    const float* Wd = (const float*)d_in[2];
    const float* bd = (const float*)d_in[3];
    const float* Wu = (const float*)d_in[4];
    const float* bu = (const float*)d_in[5];
    const float* gamma = (const float*)d_in[6];
    const float* beta = (const float*)d_in[7];
    float* out = (float*)d_out;

    char* ws = (char*)d_ws;
    // region A (64 MiB @0): hs_bf (cvt -> G1, resid of G2), then y_bf (G2 -> LN, in place)
    unsigned short* hs_bf = (unsigned short*)ws;
    unsigned short* y_bf = (unsigned short*)ws;
    // region B (12 MiB @64Mi): wd_t (tpose -> G1), then partials (G2 -> LN, 1 MiB)
    unsigned short* wd_t = (unsigned short*)(ws + 67108864);
    float2* part = (float2*)(ws + 67108864);
    // region C (12 MiB @76Mi): wu_t
    unsigned short* wu_t = (unsigned short*)(ws + 67108864 + 12582912);
    // region D (32 MiB @88Mi): h
    unsigned short* h_ws = (unsigned short*)(ws + 67108864 + 2 * 12582912);

    cvt_hs<<<4096, 256, 0, stream>>>(hs, hs_bf, (BB * S * H) / 8);
    dim3 tb(32, 8);
    tpose<<<dim3(K / 32, H / 32, R), tb, 0, stream>>>(Wd, wd_t, H, K);
    tpose<<<dim3(H / 32, K / 32, R), tb, 0, stream>>>(Wu, wu_t, K, H);
    // GEMM1: h = gelu(hs_bf x Wd^T + bd), bf16; (1024/256)*16*8 = 512 blocks
    gemm_tlp<H, 0><<<(K / 256) * 16 * BB, 512, 0, stream>>>(hs_bf, wd_t, role, bd,
                                                            nullptr, h_ws, nullptr, K);
    // GEMM2: y = h x Wu^T + bu + hs_bf, bf16 in place + stats; 1024 blocks
    gemm_tlp<K, 1><<<(H / 256) * 16 * BB, 512, 0, stream>>>(h_ws, wu_t, role, bu,
                                                            hs_bf, y_bf, part, H);
    ln2<<<BB * S, 256, 0, stream>>>(y_bf, part, role, gamma, beta, out);
}